// Round 14
// baseline (154.611 us; speedup 1.0000x reference)
//
#include <hip/hip_runtime.h>
#include <cstddef>

// B,N,C,H = 2,2048,768,12; HD=64.  bf16 MFMA everywhere, fp32 accum.
typedef __attribute__((ext_vector_type(8))) short bf16x8;
typedef __attribute__((ext_vector_type(4))) float f32x4;
typedef __attribute__((ext_vector_type(16))) float f32x16;

constexpr int Bb = 2, Nn = 2048, Cc = 768, Hh = 12, HDd = 64;
// 0.125 (HD^-1/2) * log2(e): softmax via exp2, mul folded into Q.
constexpr float QSCALE = 0.125f * 1.44269504088896340736f;

#define VMCNT(n) asm volatile("s_waitcnt vmcnt(" #n ")" ::: "memory")
#define SBAR() __builtin_amdgcn_s_barrier()

__device__ inline short f2bf(float f) {
  unsigned u = __builtin_bit_cast(unsigned, f);
  u += 0x7fff + ((u >> 16) & 1);  // RNE
  return (short)(u >> 16);
}
__device__ inline unsigned cvtpk(float a, float b) {
  unsigned r;
  asm("v_cvt_pk_bf16_f32 %0, %1, %2" : "=v"(r) : "v"(a), "v"(b));
  return r;
}
__device__ inline void gl_lds16(const void* g, void* l) {
  __builtin_amdgcn_global_load_lds(
      (const __attribute__((address_space(1))) unsigned*)g,
      (__attribute__((address_space(3))) unsigned*)l, 16, 0, 0);
}
__device__ inline bf16x8 lds8(const short* p) { return *(const bf16x8*)p; }
__device__ inline f32x16 zero16() {
  f32x16 z;
#pragma unroll
  for (int r = 0; r < 16; ++r) z[r] = 0.f;
  return z;
}
__device__ inline bf16x8 ld_frag(const short* base, int row, int ch) {
  return *(const bf16x8*)&base[row * 64 + (((ch ^ (row & 7)) << 3))];
}

// ---------------------------------------------------------------------------
// Merged f32 -> bf16 convert over three contiguous destination ranges.
// ---------------------------------------------------------------------------
__global__ __launch_bounds__(256) void cvt3_kernel(
    const float* __restrict__ s0, const float* __restrict__ s1,
    const float* __restrict__ s2, short* __restrict__ d, int n0, int n01) {
  const int i = (blockIdx.x * 256 + threadIdx.x) * 4;
  const float* src;
  int off;
  if (i < n0) {
    src = s0; off = i;
  } else if (i < n01) {
    src = s1; off = i - n0;
  } else {
    src = s2; off = i - n01;
  }
  const float4 v = *(const float4*)&src[off];
  short4 o;
  o.x = f2bf(v.x); o.y = f2bf(v.y); o.z = f2bf(v.z); o.w = f2bf(v.w);
  *(short4*)&d[i] = o;
}

// ---------------------------------------------------------------------------
// QKV GEMM (r12, frozen): 128x96 tile, grid (32,24) = 768 = 3/CU.
// ---------------------------------------------------------------------------
__global__ __launch_bounds__(256) void qkv_mfma(
    const short* __restrict__ A, const short* __restrict__ W,
    short* __restrict__ Qg, short* __restrict__ Kg, short* __restrict__ Vtg) {
  __shared__ short As[2 * 8192];   // 128 rows x 64
  __shared__ short Bs[2 * 6144];   // 96 rows x 64
  const int t = threadIdx.x, l = t & 63, w = t >> 6;
  const int lr = l & 15, lh = l >> 4;
  const int m0 = blockIdx.x * 128, r0 = blockIdx.y * 96;
  const int wr = w >> 1, wc = w & 1;
  f32x4 acc[4][3];
#pragma unroll
  for (int i = 0; i < 4; ++i)
#pragma unroll
    for (int j = 0; j < 3; ++j) acc[i][j] = (f32x4){0.f, 0.f, 0.f, 0.f};

  auto stage = [&](const int buf, const int kt) {  // 7 gl_lds / thread
#pragma unroll
    for (int u = 0; u < 4; ++u) {
      const int cu = u * 4 + w;
      const int du = cu * 64 + l;
      const int row = du >> 3, ch = du & 7, sch = ch ^ (row & 7);
      gl_lds16(A + (size_t)(m0 + row) * Cc + kt * 64 + sch * 8,
               &As[buf * 8192 + cu * 512]);
    }
#pragma unroll
    for (int u = 0; u < 3; ++u) {
      const int cu = u * 4 + w;
      const int du = cu * 64 + l;
      const int row = du >> 3, ch = du & 7, sch = ch ^ (row & 7);
      gl_lds16(W + (size_t)(r0 + row) * Cc + kt * 64 + sch * 8,
               &Bs[buf * 6144 + cu * 512]);
    }
  };
  auto compute = [&](const int buf) {
    const short* Ab = As + buf * 8192;
    const short* Bbp = Bs + buf * 6144;
#pragma unroll
    for (int kp = 0; kp < 2; ++kp) {
      bf16x8 af[4], bfv[3];
#pragma unroll
      for (int i = 0; i < 4; ++i)
        af[i] = ld_frag(Ab, wr * 64 + i * 16 + lr, kp * 4 + lh);
#pragma unroll
      for (int j = 0; j < 3; ++j)
        bfv[j] = ld_frag(Bbp, wc * 48 + j * 16 + lr, kp * 4 + lh);
      __builtin_amdgcn_s_setprio(1);
#pragma unroll
      for (int i = 0; i < 4; ++i)
#pragma unroll
        for (int j = 0; j < 3; ++j)
          acc[i][j] = __builtin_amdgcn_mfma_f32_16x16x32_bf16(
              af[i], bfv[j], acc[i][j], 0, 0, 0);
      __builtin_amdgcn_s_setprio(0);
    }
  };

  stage(0, 0);
#pragma unroll 1
  for (int kk = 0; kk < 10; kk += 2) {
    stage(1, kk + 1);
    VMCNT(7); SBAR();
    compute(0);
    SBAR();
    stage(0, kk + 2);
    VMCNT(7); SBAR();
    compute(1);
    SBAR();
  }
  stage(1, 11);
  VMCNT(7); SBAR();
  compute(0);
  SBAR();
  VMCNT(0); SBAR();
  compute(1);

  const int which = r0 / Cc;  // 96 | 768: block-uniform
  const int rbase = r0 % Cc;
  const int bq = m0 >> 11;
  const int nb = (m0 & 2047) + wr * 64;
  if (which == 2) {
#pragma unroll
    for (int j = 0; j < 3; ++j) {
      const int rr = rbase + wc * 48 + j * 16 + lr;
      const int head = rr >> 6, dd = rr & 63;
      short* vp = &Vtg[(((size_t)bq * Hh + head) * HDd + dd) * Nn];
#pragma unroll
      for (int i = 0; i < 4; ++i) {
        short4 o;
        o.x = f2bf(acc[i][j][0]); o.y = f2bf(acc[i][j][1]);
        o.z = f2bf(acc[i][j][2]); o.w = f2bf(acc[i][j][3]);
        *(short4*)&vp[nb + i * 16 + lh * 4] = o;
      }
    }
  } else {
    const float scl = (which == 0) ? QSCALE : 1.0f;
    short* __restrict__ dst = (which == 0) ? Qg : Kg;
#pragma unroll
    for (int j = 0; j < 3; ++j) {
      const int rr = rbase + wc * 48 + j * 16 + lr;
      const int head = rr >> 6, dd = rr & 63;
      short* dp = &dst[((size_t)bq * Hh + head) * Nn * HDd + dd];
#pragma unroll
      for (int i = 0; i < 4; ++i)
#pragma unroll
        for (int r = 0; r < 4; ++r)
          dp[(size_t)(nb + i * 16 + lh * 4 + r) * HDd] =
              f2bf(acc[i][j][r] * scl);
    }
  }
}

// ---------------------------------------------------------------------------
// Attention pass 1 (r8, frozen).  Grid 768 = (b, head, 64-q); 4 waves x 16 q.
// ---------------------------------------------------------------------------
__global__ __launch_bounds__(256, 3) void attn_pass1(
    const short* __restrict__ Qg, const short* __restrict__ Kg,
    const short* __restrict__ Vtg, float* __restrict__ Linv,
    short* __restrict__ OHb) {
  __shared__ short SM[4 * 4096 + 4 * 1024];
  const int t = threadIdx.x, l = t & 63, w = t >> 6;
  const int lr = l & 15, lh = l >> 4;
  const int raw = blockIdx.x;
  const int bid = (raw & 7) * 96 + (raw >> 3);
  const int q0 = (bid & 31) * 64;
  const int head = (bid >> 5) % Hh;
  const int b = bid / (32 * Hh);
  const size_t base = (size_t)b * Hh + head;
  const short* Qh = Qg + base * Nn * HDd;
  const short* Kh = Kg + base * Nn * HDd;
  const short* Vh = Vtg + base * HDd * Nn;
  const int qw = q0 + w * 16;
  const int PB = 16384 + w * 1024;

  const bf16x8 onesf = {0x3F80, 0x3F80, 0x3F80, 0x3F80,
                        0x3F80, 0x3F80, 0x3F80, 0x3F80};

  int fof[2][4], wofi[4], pof[2];
#pragma unroll
  for (int kp = 0; kp < 2; ++kp) {
#pragma unroll
    for (int i = 0; i < 4; ++i)
      fof[kp][i] = (i * 16 + lr) * 64 + (((kp * 4 + lh) ^ (lr & 7)) << 3);
    pof[kp] = lr * 64 + (((kp * 4 + lh) ^ (lr & 7)) << 3);
  }
#pragma unroll
  for (int i = 0; i < 4; ++i) {
    const int ch = 2 * i + (lh >> 1);
    wofi[i] = lr * 64 + ((ch ^ (lr & 7)) << 3) + (lh & 1) * 4;
  }

  bf16x8 qf[2];
#pragma unroll
  for (int kp = 0; kp < 2; ++kp)
    qf[kp] = *(const bf16x8*)&Qh[(size_t)(qw + lr) * HDd + kp * 32 + lh * 8];

  f32x4 accO[4], accL;
  accL = (f32x4){0.f, 0.f, 0.f, 0.f};
#pragma unroll
  for (int j = 0; j < 4; ++j) accO[j] = (f32x4){0.f, 0.f, 0.f, 0.f};

  auto stage = [&](const int buf, const int tile) {
    const short* Kt = Kh + (size_t)tile * (64 * HDd);
    const short* Vt = Vh + tile * 64;
#pragma unroll
    for (int u = 0; u < 2; ++u) {
      const int cu = u * 4 + w;
      const int du = cu * 64 + l;
      const int row = du >> 3, ch = du & 7, sch = ch ^ (row & 7);
      gl_lds16(Kt + row * 64 + sch * 8, &SM[buf * 4096 + cu * 512]);
      gl_lds16(Vt + (size_t)row * Nn + sch * 8,
               &SM[8192 + buf * 4096 + cu * 512]);
    }
  };

  auto compute = [&](const int kb) {
    const int vb = 8192 + kb;
    f32x4 sacc[4];
#pragma unroll
    for (int i = 0; i < 4; ++i) sacc[i] = (f32x4){0.f, 0.f, 0.f, 0.f};
    __builtin_amdgcn_s_setprio(1);
#pragma unroll
    for (int kp = 0; kp < 2; ++kp)
#pragma unroll
      for (int i = 0; i < 4; ++i)
        sacc[i] = __builtin_amdgcn_mfma_f32_16x16x32_bf16(
            lds8(&SM[kb + fof[kp][i]]), qf[kp], sacc[i], 0, 0, 0);
    __builtin_amdgcn_s_setprio(0);
#pragma unroll
    for (int i = 0; i < 4; ++i) {
      const float p0 = exp2f(sacc[i][0]), p1 = exp2f(sacc[i][1]);
      const float p2 = exp2f(sacc[i][2]), p3 = exp2f(sacc[i][3]);
      uint2 pk;
      pk.x = cvtpk(p0, p1);
      pk.y = cvtpk(p2, p3);
      *(uint2*)&SM[PB + wofi[i]] = pk;
    }
    __builtin_amdgcn_s_setprio(1);
#pragma unroll
    for (int kp = 0; kp < 2; ++kp) {
      const bf16x8 pa = lds8(&SM[PB + pof[kp]]);
      accL = __builtin_amdgcn_mfma_f32_16x16x32_bf16(pa, onesf, accL, 0, 0, 0);
#pragma unroll
      for (int j = 0; j < 4; ++j)
        accO[j] = __builtin_amdgcn_mfma_f32_16x16x32_bf16(
            pa, lds8(&SM[vb + fof[kp][j]]), accO[j], 0, 0, 0);
    }
    __builtin_amdgcn_s_setprio(0);
  };

  stage(0, 0);
#pragma unroll 1
  for (int it = 0; it < 30; it += 2) {
    stage(1, it + 1);
    VMCNT(4); SBAR();
    compute(0);
    SBAR();
    stage(0, it + 2);
    VMCNT(4); SBAR();
    compute(4096);
    SBAR();
  }
  stage(1, 31);
  VMCNT(4); SBAR();
  compute(0);  // tile 30
  SBAR();
  VMCNT(0); SBAR();
  compute(4096);  // tile 31

  f32x4 linvq;
#pragma unroll
  for (int r = 0; r < 4; ++r) linvq[r] = 1.0f / accL[r];
  if (lr == 0) *(f32x4*)&Linv[base * Nn + qw + 4 * lh] = linvq;
#pragma unroll
  for (int j = 0; j < 4; ++j)
#pragma unroll
    for (int r = 0; r < 4; ++r)
      OHb[((size_t)b * Nn + qw + 4 * lh + r) * Cc + head * HDd + j * 16 + lr] =
          f2bf(accO[j][r] * linvq[r]);
}

// ---------------------------------------------------------------------------
// Score v3: 32x32 swapped QK (r7/r13-verified) + r8's head-pipelined A/B
// schedule: exp(h-1)*linv overlaps QK(h).  4 waves x 32 q, q-tile 128, grid
// 1024.  Double sacc (named sA*/sB*, static).  Epilogue: [128][66] LDS
// staging -> 256B contiguous stores (r13-verified).
// ---------------------------------------------------------------------------
__global__ __launch_bounds__(256, 3) void score_mfma(
    const short* __restrict__ Qg, const short* __restrict__ Kg,
    const float* __restrict__ Linv, float* __restrict__ score) {
  __shared__ __align__(16) char SMraw[128 * 66 * 4];  // 33792 B
  short* SK = (short*)SMraw;    // K dbuf: 2 x 4096 shorts (16 KB)
  float* SOUT = (float*)SMraw;  // [128][66] f32 out staging (after loop)
  const int t = threadIdx.x, l = t & 63, w = t >> 6;
  const int lo5 = l & 31, hi5 = l >> 5;
  // XCD map: xcd -> (b = xcd>>2, 4 q-tiles of 128) x 32 kv-tiles
  const int raw = blockIdx.x;  // 1024
  const int xcd = raw & 7, idx = raw >> 3;
  const int b = xcd >> 2;
  const int q0 = ((xcd & 3) * 4 + (idx >> 5)) * 128;
  const int kv0 = (idx & 31) * 64;
  const int qw = q0 + w * 32;

  int of2[2][4];
#pragma unroll
  for (int i = 0; i < 2; ++i)
#pragma unroll
    for (int s = 0; s < 4; ++s)
      of2[i][s] = (i * 32 + lo5) * 64 + ((((2 * s + hi5) ^ (l & 7))) << 3);

  f32x16 sc0 = zero16(), sc1 = zero16();

  auto stage = [&](const int kb, const int h) {
    const short* Kt = Kg + (((size_t)b * Hh + h) * Nn + kv0) * HDd;
#pragma unroll
    for (int u = 0; u < 2; ++u) {
      const int cu = u * 4 + w;
      const int du = cu * 64 + l;
      const int row = du >> 3, ch = du & 7, sch = ch ^ (row & 7);
      gl_lds16(Kt + row * 64 + sch * 8, &SK[kb + cu * 512]);
    }
  };
  auto ldq = [&](const int h, bf16x8& f0, bf16x8& f1, bf16x8& f2,
                 bf16x8& f3) {
    const short* Qh = Qg + ((size_t)b * Hh + h) * Nn * HDd;
    f0 = *(const bf16x8*)&Qh[(size_t)(qw + lo5) * HDd + 0 + hi5 * 8];
    f1 = *(const bf16x8*)&Qh[(size_t)(qw + lo5) * HDd + 16 + hi5 * 8];
    f2 = *(const bf16x8*)&Qh[(size_t)(qw + lo5) * HDd + 32 + hi5 * 8];
    f3 = *(const bf16x8*)&Qh[(size_t)(qw + lo5) * HDd + 48 + hi5 * 8];
  };
  auto qk = [&](const int kb, const bf16x8 f0, const bf16x8 f1,
                const bf16x8 f2, const bf16x8 f3, f32x16& s0, f32x16& s1) {
    s0 = zero16();
    s1 = zero16();
    __builtin_amdgcn_s_setprio(1);
    s0 = __builtin_amdgcn_mfma_f32_32x32x16_bf16(lds8(&SK[kb + of2[0][0]]),
                                                 f0, s0, 0, 0, 0);
    s1 = __builtin_amdgcn_mfma_f32_32x32x16_bf16(lds8(&SK[kb + of2[1][0]]),
                                                 f0, s1, 0, 0, 0);
    s0 = __builtin_amdgcn_mfma_f32_32x32x16_bf16(lds8(&SK[kb + of2[0][1]]),
                                                 f1, s0, 0, 0, 0);
    s1 = __builtin_amdgcn_mfma_f32_32x32x16_bf16(lds8(&SK[kb + of2[1][1]]),
                                                 f1, s1, 0, 0, 0);
    s0 = __builtin_amdgcn_mfma_f32_32x32x16_bf16(lds8(&SK[kb + of2[0][2]]),
                                                 f2, s0, 0, 0, 0);
    s1 = __builtin_amdgcn_mfma_f32_32x32x16_bf16(lds8(&SK[kb + of2[1][2]]),
                                                 f2, s1, 0, 0, 0);
    s0 = __builtin_amdgcn_mfma_f32_32x32x16_bf16(lds8(&SK[kb + of2[0][3]]),
                                                 f3, s0, 0, 0, 0);
    s1 = __builtin_amdgcn_mfma_f32_32x32x16_bf16(lds8(&SK[kb + of2[1][3]]),
                                                 f3, s1, 0, 0, 0);
    __builtin_amdgcn_s_setprio(0);
  };
  auto expacc = [&](const f32x16& s0, const f32x16& s1, const float lv) {
#pragma unroll
    for (int r = 0; r < 16; ++r) {
      sc0[r] += exp2f(s0[r]) * lv;
      sc1[r] += exp2f(s1[r]) * lv;
    }
  };

  bf16x8 qA0, qA1, qA2, qA3, qB0, qB1, qB2, qB3;
  f32x16 sA0, sA1, sB0, sB1;
  float lvA, lvB;
  // prologue
  stage(0, 0);
  ldq(0, qA0, qA1, qA2, qA3);
  __syncthreads();
  stage(4096, 1);
  ldq(1, qB0, qB1, qB2, qB3);
  lvA = Linv[((size_t)b * Hh + 0) * Nn + qw + lo5];
  qk(0, qA0, qA1, qA2, qA3, sA0, sA1);
  __syncthreads();
#pragma unroll 1
  for (int h = 1; h < 11; h += 2) {
    // first half: head h (buf1) computes, head h-1 (sA) exps
    stage(0, h + 1);
    ldq(h + 1, qA0, qA1, qA2, qA3);
    lvB = Linv[((size_t)b * Hh + h) * Nn + qw + lo5];
    qk(4096, qB0, qB1, qB2, qB3, sB0, sB1);
    expacc(sA0, sA1, lvA);
    __syncthreads();
    // second half: head h+1 (buf0) computes, head h (sB) exps
    stage(4096, h + 2);
    ldq(h + 2, qB0, qB1, qB2, qB3);
    lvA = Linv[((size_t)b * Hh + h + 1) * Nn + qw + lo5];
    qk(0, qA0, qA1, qA2, qA3, sA0, sA1);
    expacc(sB0, sB1, lvB);
    __syncthreads();
  }
  // epilogue: head 11 (buf1)
  lvB = Linv[((size_t)b * Hh + 11) * Nn + qw + lo5];
  qk(4096, qB0, qB1, qB2, qB3, sB0, sB1);
  expacc(sA0, sA1, lvA);
  expacc(sB0, sB1, lvB);
  __syncthreads();  // all K reads done before LDS reuse

  // epilogue: reuse LDS as [128][66] f32; D row->kv map (m74):
  // kv = (r&3) + 8*(r>>2) + 4*hi5 ; r = 4g+e is a contiguous f32x4.
  constexpr float invH = 1.0f / 12.0f;
  const int qrow = (w * 32 + lo5) * 66;
#pragma unroll
  for (int g = 0; g < 4; ++g) {
    f32x4 o0, o1;
#pragma unroll
    for (int e = 0; e < 4; ++e) {
      o0[e] = sc0[4 * g + e] * invH;
      o1[e] = sc1[4 * g + e] * invH;
    }
    *(f32x4*)&SOUT[qrow + 8 * g + 4 * hi5] = o0;
    *(f32x4*)&SOUT[qrow + 32 + 8 * g + 4 * hi5] = o1;
  }
  __syncthreads();
#pragma unroll
  for (int s = 0; s < 8; ++s) {
    const int unit = s * 256 + t;              // 2048 f32x4 units
    const int row = unit >> 4, c = unit & 15;  // 16 units = one row's 256B
    const f32x4 v = *(const f32x4*)&SOUT[row * 66 + c * 4];
    *(f32x4*)&score[((size_t)b * Nn + q0 + row) * Nn + kv0 + c * 4] = v;
  }
}

// ---------------------------------------------------------------------------
// Proj GEMM (r12, frozen): 64x64 tile, grid (64,12) = 768 = 3/CU.
// ---------------------------------------------------------------------------
__global__ __launch_bounds__(256) void proj_mfma(
    const short* __restrict__ A, const short* __restrict__ W,
    const float* __restrict__ bias, float* __restrict__ out) {
  __shared__ short As[2 * 4096];
  __shared__ short Bs[2 * 4096];
  const int t = threadIdx.x, l = t & 63, w = t >> 6;
  const int lr = l & 15, lh = l >> 4;
  const int m0 = blockIdx.x * 64, c0 = blockIdx.y * 64;
  const int wr = w >> 1, wc = w & 1;
  f32x4 acc[2][2];
#pragma unroll
  for (int i = 0; i < 2; ++i)
#pragma unroll
    for (int j = 0; j < 2; ++j) acc[i][j] = (f32x4){0.f, 0.f, 0.f, 0.f};

  auto stage = [&](const int buf, const int kt) {
#pragma unroll
    for (int u = 0; u < 2; ++u) {
      const int cu = u * 4 + w;
      const int du = cu * 64 + l;
      const int row = du >> 3, ch = du & 7, sch = ch ^ (row & 7);
      gl_lds16(A + (size_t)(m0 + row) * Cc + kt * 64 + sch * 8,
               &As[buf * 4096 + cu * 512]);
      gl_lds16(W + (size_t)(c0 + row) * Cc + kt * 64 + sch * 8,
               &Bs[buf * 4096 + cu * 512]);
    }
  };
  auto compute = [&](const int buf) {
    const short* Ab = As + buf * 4096;
    const short* Bbp = Bs + buf * 4096;
#pragma unroll
    for (int kp = 0; kp < 2; ++kp) {
      bf16x8 af[2], bfv[2];
#pragma unroll
      for (int i = 0; i < 2; ++i)
        af[i] = ld_frag(Ab, wr * 32 + i * 16 + lr, kp * 4 + lh);
#pragma unroll
      for (int j = 0; j < 2; ++j)
        bfv[j] = ld_frag(Bbp, wc * 32 + j * 16 + lr, kp * 4 + lh);
      __builtin_amdgcn_s_setprio(1);
#pragma unroll
      for (int i = 0; i < 2; ++i)
#pragma unroll
        for (int j = 0; j < 2; ++j)
          acc[i][j] = __builtin_amdgcn_mfma_f32_16x16x32_bf16(
              af[i], bfv[j], acc[i][j], 0, 0, 0);
      __builtin_amdgcn_s_setprio(0);
    }
  };

  stage(0, 0);
#pragma unroll 1
  for (int kk = 0; kk < 10; kk += 2) {
    stage(1, kk + 1);
    VMCNT(4); SBAR();
    compute(0);
    SBAR();
    stage(0, kk + 2);
    VMCNT(4); SBAR();
    compute(1);
    SBAR();
  }
  stage(1, 11);
  VMCNT(4); SBAR();
  compute(0);
  SBAR();
  VMCNT(0); SBAR();
  compute(1);

#pragma unroll
  for (int j = 0; j < 2; ++j) {
    const int c = c0 + wc * 32 + j * 16 + lr;
    const float bi = bias[c];
#pragma unroll
    for (int i = 0; i < 2; ++i)
#pragma unroll
      for (int r = 0; r < 4; ++r) {
        const int m = m0 + wr * 32 + i * 16 + lh * 4 + r;
        out[(size_t)m * Cc + c] = acc[i][j][r] + bi;
      }
  }
}

// ---------------------------------------------------------------------------
extern "C" void kernel_launch(void* const* d_in, const int* in_sizes, int n_in,
                              void* d_out, int out_size, void* d_ws,
                              size_t ws_size, hipStream_t stream) {
  const float* x = (const float*)d_in[0];
  const float* qkv_w = (const float*)d_in[1];
  const float* proj_w = (const float*)d_in[2];
  const float* proj_b = (const float*)d_in[3];

  float* out = (float*)d_out;
  float* score = out + (size_t)Bb * Nn * Cc;

  const size_t nx = (size_t)Bb * Nn * Cc;   // 3,145,728
  const size_t nwq = (size_t)3 * Cc * Cc;   // 1,769,472
  const size_t npw = (size_t)Cc * Cc;       // 589,824
  short* xb = (short*)d_ws;
  short* wqb = xb + nx;
  short* pwb = wqb + nwq;
  short* Qb = pwb + npw;
  short* Kb = Qb + nx;
  short* Vtb = Kb + nx;
  short* OHb = Vtb + nx;
  float* Linv = (float*)(OHb + nx);

  const int ncvt = (int)((nx + nwq + npw) / 1024);  // 5376 blocks
  cvt3_kernel<<<dim3(ncvt), 256, 0, stream>>>(x, qkv_w, proj_w, xb, (int)nx,
                                              (int)(nx + nwq));
  qkv_mfma<<<dim3(32, 24), 256, 0, stream>>>(xb, wqb, Qb, Kb, Vtb);
  attn_pass1<<<dim3(768), 256, 0, stream>>>(Qb, Kb, Vtb, Linv, OHb);
  score_mfma<<<dim3(1024), 256, 0, stream>>>(Qb, Kb, Linv, score);
  proj_mfma<<<dim3(64, 12), 256, 0, stream>>>(OHb, pwb, proj_b, out);
}

// Round 15
// 125.396 us; speedup vs baseline: 1.2330x; 1.2330x over previous
//
#include <hip/hip_runtime.h>
#include <cstddef>

// B,N,C,H = 2,2048,768,12; HD=64.  bf16 MFMA everywhere, fp32 accum.
typedef __attribute__((ext_vector_type(8))) short bf16x8;
typedef __attribute__((ext_vector_type(4))) float f32x4;

constexpr int Bb = 2, Nn = 2048, Cc = 768, Hh = 12, HDd = 64;
// 0.125 (HD^-1/2) * log2(e): softmax via exp2, mul folded into Q.
constexpr float QSCALE = 0.125f * 1.44269504088896340736f;

#define VMCNT(n) asm volatile("s_waitcnt vmcnt(" #n ")" ::: "memory")
#define SBAR() __builtin_amdgcn_s_barrier()

__device__ inline short f2bf(float f) {
  unsigned u = __builtin_bit_cast(unsigned, f);
  u += 0x7fff + ((u >> 16) & 1);  // RNE
  return (short)(u >> 16);
}
__device__ inline unsigned cvtpk(float a, float b) {
  unsigned r;
  asm("v_cvt_pk_bf16_f32 %0, %1, %2" : "=v"(r) : "v"(a), "v"(b));
  return r;
}
__device__ inline void gl_lds16(const void* g, void* l) {
  __builtin_amdgcn_global_load_lds(
      (const __attribute__((address_space(1))) unsigned*)g,
      (__attribute__((address_space(3))) unsigned*)l, 16, 0, 0);
}
__device__ inline bf16x8 lds8(const short* p) { return *(const bf16x8*)p; }
__device__ inline bf16x8 ld_frag(const short* base, int row, int ch) {
  return *(const bf16x8*)&base[row * 64 + (((ch ^ (row & 7)) << 3))];
}

// ---------------------------------------------------------------------------
// Merged f32 -> bf16 convert over three contiguous destination ranges.
// ---------------------------------------------------------------------------
__global__ __launch_bounds__(256) void cvt3_kernel(
    const float* __restrict__ s0, const float* __restrict__ s1,
    const float* __restrict__ s2, short* __restrict__ d, int n0, int n01) {
  const int i = (blockIdx.x * 256 + threadIdx.x) * 4;
  const float* src;
  int off;
  if (i < n0) {
    src = s0; off = i;
  } else if (i < n01) {
    src = s1; off = i - n0;
  } else {
    src = s2; off = i - n01;
  }
  const float4 v = *(const float4*)&src[off];
  short4 o;
  o.x = f2bf(v.x); o.y = f2bf(v.y); o.z = f2bf(v.z); o.w = f2bf(v.w);
  *(short4*)&d[i] = o;
}

// ---------------------------------------------------------------------------
// QKV GEMM (r12): 128x96 tile, grid (32,24) = 768 = 3 blocks/CU (balanced).
// ---------------------------------------------------------------------------
__global__ __launch_bounds__(256) void qkv_mfma(
    const short* __restrict__ A, const short* __restrict__ W,
    short* __restrict__ Qg, short* __restrict__ Kg, short* __restrict__ Vtg) {
  __shared__ short As[2 * 8192];   // 128 rows x 64
  __shared__ short Bs[2 * 6144];   // 96 rows x 64
  const int t = threadIdx.x, l = t & 63, w = t >> 6;
  const int lr = l & 15, lh = l >> 4;
  const int m0 = blockIdx.x * 128, r0 = blockIdx.y * 96;
  const int wr = w >> 1, wc = w & 1;
  f32x4 acc[4][3];
#pragma unroll
  for (int i = 0; i < 4; ++i)
#pragma unroll
    for (int j = 0; j < 3; ++j) acc[i][j] = (f32x4){0.f, 0.f, 0.f, 0.f};

  auto stage = [&](const int buf, const int kt) {  // 7 gl_lds / thread
#pragma unroll
    for (int u = 0; u < 4; ++u) {
      const int cu = u * 4 + w;
      const int du = cu * 64 + l;
      const int row = du >> 3, ch = du & 7, sch = ch ^ (row & 7);
      gl_lds16(A + (size_t)(m0 + row) * Cc + kt * 64 + sch * 8,
               &As[buf * 8192 + cu * 512]);
    }
#pragma unroll
    for (int u = 0; u < 3; ++u) {
      const int cu = u * 4 + w;
      const int du = cu * 64 + l;
      const int row = du >> 3, ch = du & 7, sch = ch ^ (row & 7);
      gl_lds16(W + (size_t)(r0 + row) * Cc + kt * 64 + sch * 8,
               &Bs[buf * 6144 + cu * 512]);
    }
  };
  auto compute = [&](const int buf) {
    const short* Ab = As + buf * 8192;
    const short* Bbp = Bs + buf * 6144;
#pragma unroll
    for (int kp = 0; kp < 2; ++kp) {
      bf16x8 af[4], bfv[3];
#pragma unroll
      for (int i = 0; i < 4; ++i)
        af[i] = ld_frag(Ab, wr * 64 + i * 16 + lr, kp * 4 + lh);
#pragma unroll
      for (int j = 0; j < 3; ++j)
        bfv[j] = ld_frag(Bbp, wc * 48 + j * 16 + lr, kp * 4 + lh);
      __builtin_amdgcn_s_setprio(1);
#pragma unroll
      for (int i = 0; i < 4; ++i)
#pragma unroll
        for (int j = 0; j < 3; ++j)
          acc[i][j] = __builtin_amdgcn_mfma_f32_16x16x32_bf16(
              af[i], bfv[j], acc[i][j], 0, 0, 0);
      __builtin_amdgcn_s_setprio(0);
    }
  };

  stage(0, 0);
#pragma unroll 1
  for (int kk = 0; kk < 10; kk += 2) {
    stage(1, kk + 1);
    VMCNT(7); SBAR();
    compute(0);
    SBAR();
    stage(0, kk + 2);
    VMCNT(7); SBAR();
    compute(1);
    SBAR();
  }
  stage(1, 11);
  VMCNT(7); SBAR();
  compute(0);
  SBAR();
  VMCNT(0); SBAR();
  compute(1);

  const int which = r0 / Cc;  // 96 | 768: block-uniform
  const int rbase = r0 % Cc;
  const int bq = m0 >> 11;
  const int nb = (m0 & 2047) + wr * 64;
  if (which == 2) {  // V: transposed layout -> short4 stores along n
#pragma unroll
    for (int j = 0; j < 3; ++j) {
      const int rr = rbase + wc * 48 + j * 16 + lr;
      const int head = rr >> 6, dd = rr & 63;
      short* vp = &Vtg[(((size_t)bq * Hh + head) * HDd + dd) * Nn];
#pragma unroll
      for (int i = 0; i < 4; ++i) {
        short4 o;
        o.x = f2bf(acc[i][j][0]); o.y = f2bf(acc[i][j][1]);
        o.z = f2bf(acc[i][j][2]); o.w = f2bf(acc[i][j][3]);
        *(short4*)&vp[nb + i * 16 + lh * 4] = o;
      }
    }
  } else {
    const float scl = (which == 0) ? QSCALE : 1.0f;
    short* __restrict__ dst = (which == 0) ? Qg : Kg;
#pragma unroll
    for (int j = 0; j < 3; ++j) {
      const int rr = rbase + wc * 48 + j * 16 + lr;
      const int head = rr >> 6, dd = rr & 63;
      short* dp = &dst[((size_t)bq * Hh + head) * Nn * HDd + dd];
#pragma unroll
      for (int i = 0; i < 4; ++i)
#pragma unroll
        for (int r = 0; r < 4; ++r)
          dp[(size_t)(nb + i * 16 + lh * 4 + r) * HDd] =
              f2bf(acc[i][j][r] * scl);
    }
  }
}

// ---------------------------------------------------------------------------
// Attention pass 1 (r8).  Grid 768 = (b, head, 64-q); 4 waves x 16 q.
// K/V dbuf, counted vmcnt, raw barriers, setprio, L via mfma(P, ones).
// ---------------------------------------------------------------------------
__global__ __launch_bounds__(256, 3) void attn_pass1(
    const short* __restrict__ Qg, const short* __restrict__ Kg,
    const short* __restrict__ Vtg, float* __restrict__ Linv,
    short* __restrict__ OHb) {
  __shared__ short SM[4 * 4096 + 4 * 1024];
  const int t = threadIdx.x, l = t & 63, w = t >> 6;
  const int lr = l & 15, lh = l >> 4;
  const int raw = blockIdx.x;
  const int bid = (raw & 7) * 96 + (raw >> 3);
  const int q0 = (bid & 31) * 64;
  const int head = (bid >> 5) % Hh;
  const int b = bid / (32 * Hh);
  const size_t base = (size_t)b * Hh + head;
  const short* Qh = Qg + base * Nn * HDd;
  const short* Kh = Kg + base * Nn * HDd;
  const short* Vh = Vtg + base * HDd * Nn;
  const int qw = q0 + w * 16;
  const int PB = 16384 + w * 1024;

  const bf16x8 onesf = {0x3F80, 0x3F80, 0x3F80, 0x3F80,
                        0x3F80, 0x3F80, 0x3F80, 0x3F80};

  int fof[2][4], wofi[4], pof[2];
#pragma unroll
  for (int kp = 0; kp < 2; ++kp) {
#pragma unroll
    for (int i = 0; i < 4; ++i)
      fof[kp][i] = (i * 16 + lr) * 64 + (((kp * 4 + lh) ^ (lr & 7)) << 3);
    pof[kp] = lr * 64 + (((kp * 4 + lh) ^ (lr & 7)) << 3);
  }
#pragma unroll
  for (int i = 0; i < 4; ++i) {
    const int ch = 2 * i + (lh >> 1);
    wofi[i] = lr * 64 + ((ch ^ (lr & 7)) << 3) + (lh & 1) * 4;
  }

  bf16x8 qf[2];
#pragma unroll
  for (int kp = 0; kp < 2; ++kp)
    qf[kp] = *(const bf16x8*)&Qh[(size_t)(qw + lr) * HDd + kp * 32 + lh * 8];

  f32x4 accO[4], accL;
  accL = (f32x4){0.f, 0.f, 0.f, 0.f};
#pragma unroll
  for (int j = 0; j < 4; ++j) accO[j] = (f32x4){0.f, 0.f, 0.f, 0.f};

  auto stage = [&](const int buf, const int tile) {
    const short* Kt = Kh + (size_t)tile * (64 * HDd);
    const short* Vt = Vh + tile * 64;
#pragma unroll
    for (int u = 0; u < 2; ++u) {
      const int cu = u * 4 + w;
      const int du = cu * 64 + l;
      const int row = du >> 3, ch = du & 7, sch = ch ^ (row & 7);
      gl_lds16(Kt + row * 64 + sch * 8, &SM[buf * 4096 + cu * 512]);
      gl_lds16(Vt + (size_t)row * Nn + sch * 8,
               &SM[8192 + buf * 4096 + cu * 512]);
    }
  };

  auto compute = [&](const int kb) {
    const int vb = 8192 + kb;
    f32x4 sacc[4];
#pragma unroll
    for (int i = 0; i < 4; ++i) sacc[i] = (f32x4){0.f, 0.f, 0.f, 0.f};
    __builtin_amdgcn_s_setprio(1);
#pragma unroll
    for (int kp = 0; kp < 2; ++kp)
#pragma unroll
      for (int i = 0; i < 4; ++i)
        sacc[i] = __builtin_amdgcn_mfma_f32_16x16x32_bf16(
            lds8(&SM[kb + fof[kp][i]]), qf[kp], sacc[i], 0, 0, 0);
    __builtin_amdgcn_s_setprio(0);
#pragma unroll
    for (int i = 0; i < 4; ++i) {
      const float p0 = exp2f(sacc[i][0]), p1 = exp2f(sacc[i][1]);
      const float p2 = exp2f(sacc[i][2]), p3 = exp2f(sacc[i][3]);
      uint2 pk;
      pk.x = cvtpk(p0, p1);
      pk.y = cvtpk(p2, p3);
      *(uint2*)&SM[PB + wofi[i]] = pk;
    }
    __builtin_amdgcn_s_setprio(1);
#pragma unroll
    for (int kp = 0; kp < 2; ++kp) {
      const bf16x8 pa = lds8(&SM[PB + pof[kp]]);
      accL = __builtin_amdgcn_mfma_f32_16x16x32_bf16(pa, onesf, accL, 0, 0, 0);
#pragma unroll
      for (int j = 0; j < 4; ++j)
        accO[j] = __builtin_amdgcn_mfma_f32_16x16x32_bf16(
            pa, lds8(&SM[vb + fof[kp][j]]), accO[j], 0, 0, 0);
    }
    __builtin_amdgcn_s_setprio(0);
  };

  stage(0, 0);
#pragma unroll 1
  for (int it = 0; it < 30; it += 2) {
    stage(1, it + 1);
    VMCNT(4); SBAR();
    compute(0);
    SBAR();
    stage(0, it + 2);
    VMCNT(4); SBAR();
    compute(4096);
    SBAR();
  }
  stage(1, 31);
  VMCNT(4); SBAR();
  compute(0);  // tile 30
  SBAR();
  VMCNT(0); SBAR();
  compute(4096);  // tile 31

  f32x4 linvq;
#pragma unroll
  for (int r = 0; r < 4; ++r) linvq[r] = 1.0f / accL[r];
  if (lr == 0) *(f32x4*)&Linv[base * Nn + qw + 4 * lh] = linvq;
#pragma unroll
  for (int j = 0; j < 4; ++j)
#pragma unroll
    for (int r = 0; r < 4; ++r)
      OHb[((size_t)b * Nn + qw + 4 * lh + r) * Cc + head * HDd + j * 16 + lr] =
          f2bf(accO[j][r] * linvq[r]);
}

// ---------------------------------------------------------------------------
// Score (r8): score[b][q][kv] = (1/H) sum_h 2^(qk) * Linv[b,h,q].
// Grid 2048 = (b, 64-q, 64-kv); 4 waves x 16 q, phase-shifted over heads.
// ---------------------------------------------------------------------------
__global__ __launch_bounds__(256, 4) void score_mfma(
    const short* __restrict__ Qg, const short* __restrict__ Kg,
    const float* __restrict__ Linv, float* __restrict__ score) {
  __shared__ __align__(16) char SMraw[64 * 68 * 4];  // 17408 B
  short* SK = (short*)SMraw;   // K dbuf: 2 x 4096 shorts (16 KB)
  float* SMf = (float*)SMraw;  // out staging [64][68] after the loop
  const int t = threadIdx.x, l = t & 63, w = t >> 6;
  const int lr = l & 15, lh = l >> 4;
  const int raw = blockIdx.x;  // 2048
  const int xcd = raw & 7, idx = raw >> 3;
  const int b = xcd >> 2;
  const int q0 = ((xcd & 3) * 8 + (idx >> 5)) * 64;
  const int kv0 = (idx & 31) * 64;
  const int qw = q0 + w * 16;

  int fof[2][4];
#pragma unroll
  for (int kp = 0; kp < 2; ++kp)
#pragma unroll
    for (int i = 0; i < 4; ++i)
      fof[kp][i] = (i * 16 + lr) * 64 + (((kp * 4 + lh) ^ (lr & 7)) << 3);

  f32x4 sc[4];
#pragma unroll
  for (int i = 0; i < 4; ++i) sc[i] = (f32x4){0.f, 0.f, 0.f, 0.f};

  auto stage = [&](const int kb, const int h) {
    const short* Kt = Kg + (((size_t)b * Hh + h) * Nn + kv0) * HDd;
#pragma unroll
    for (int u = 0; u < 2; ++u) {
      const int cu = u * 4 + w;
      const int du = cu * 64 + l;
      const int row = du >> 3, ch = du & 7, sch = ch ^ (row & 7);
      gl_lds16(Kt + row * 64 + sch * 8, &SK[kb + cu * 512]);
    }
  };
  auto ldqQ = [&](const int h, bf16x8& a0, bf16x8& a1) {
    const size_t hb = (size_t)b * Hh + h;
    a0 = *(const bf16x8*)&Qg[(hb * Nn + qw + lr) * HDd + lh * 8];
    a1 = *(const bf16x8*)&Qg[(hb * Nn + qw + lr) * HDd + 32 + lh * 8];
  };
  auto qk = [&](const int kb, const bf16x8 a0, const bf16x8 a1,
                f32x4 (&sacc)[4]) {
#pragma unroll
    for (int i = 0; i < 4; ++i) sacc[i] = (f32x4){0.f, 0.f, 0.f, 0.f};
#pragma unroll
    for (int i = 0; i < 4; ++i)
      sacc[i] = __builtin_amdgcn_mfma_f32_16x16x32_bf16(
          lds8(&SK[kb + fof[0][i]]), a0, sacc[i], 0, 0, 0);
#pragma unroll
    for (int i = 0; i < 4; ++i)
      sacc[i] = __builtin_amdgcn_mfma_f32_16x16x32_bf16(
          lds8(&SK[kb + fof[1][i]]), a1, sacc[i], 0, 0, 0);
  };
  auto expacc = [&](const f32x4 (&sacc)[4], const float lv) {
#pragma unroll
    for (int i = 0; i < 4; ++i)
#pragma unroll
      for (int r = 0; r < 4; ++r) sc[i][r] += exp2f(sacc[i][r]) * lv;
  };

  bf16x8 qA0, qA1, qB0, qB1;
  float lvA, lvB;
  f32x4 sA[4], sB[4];
  stage(0, 0);
  ldqQ(0, qA0, qA1);
  __syncthreads();
  stage(4096, 1);
  ldqQ(1, qB0, qB1);
  lvA = Linv[((size_t)b * Hh + 0) * Nn + qw + lr];
  qk(0, qA0, qA1, sA);
  __syncthreads();
#pragma unroll 1
  for (int h = 1; h < 11; h += 2) {
    stage(0, h + 1);
    ldqQ(h + 1, qA0, qA1);
    lvB = Linv[((size_t)b * Hh + h) * Nn + qw + lr];
    qk(4096, qB0, qB1, sB);
    expacc(sA, lvA);
    __syncthreads();
    stage(4096, h + 2);
    ldqQ(h + 2, qB0, qB1);
    lvA = Linv[((size_t)b * Hh + h + 1) * Nn + qw + lr];
    qk(0, qA0, qA1, sA);
    expacc(sB, lvB);
    __syncthreads();
  }
  lvB = Linv[((size_t)b * Hh + 11) * Nn + qw + lr];
  qk(4096, qB0, qB1, sB);
  expacc(sA, lvA);
  expacc(sB, lvB);
  __syncthreads();  // all K reads done before LDS reuse

  constexpr float invH = 1.0f / 12.0f;
#pragma unroll
  for (int i = 0; i < 4; ++i) {
    f32x4 o;
#pragma unroll
    for (int r = 0; r < 4; ++r) o[r] = sc[i][r] * invH;
    *(f32x4*)&SMf[(w * 16 + lr) * 68 + i * 16 + 4 * lh] = o;
  }
  __syncthreads();
#pragma unroll
  for (int s = 0; s < 4; ++s) {
    const int lin = t + s * 256;
    const int row = lin >> 4, ch = lin & 15;  // 16 threads = one 256B row
    const f32x4 v = *(const f32x4*)&SMf[row * 68 + ch * 4];
    *(f32x4*)&score[((size_t)b * Nn + q0 + row) * Nn + kv0 + ch * 4] = v;
  }
}

// ---------------------------------------------------------------------------
// Proj GEMM (r12): 64x64 tile, grid (64,12) = 768 = 3/CU.
// ---------------------------------------------------------------------------
__global__ __launch_bounds__(256) void proj_mfma(
    const short* __restrict__ A, const short* __restrict__ W,
    const float* __restrict__ bias, float* __restrict__ out) {
  __shared__ short As[2 * 4096];
  __shared__ short Bs[2 * 4096];
  const int t = threadIdx.x, l = t & 63, w = t >> 6;
  const int lr = l & 15, lh = l >> 4;
  const int m0 = blockIdx.x * 64, c0 = blockIdx.y * 64;
  const int wr = w >> 1, wc = w & 1;
  f32x4 acc[2][2];
#pragma unroll
  for (int i = 0; i < 2; ++i)
#pragma unroll
    for (int j = 0; j < 2; ++j) acc[i][j] = (f32x4){0.f, 0.f, 0.f, 0.f};

  auto stage = [&](const int buf, const int kt) {
#pragma unroll
    for (int u = 0; u < 2; ++u) {
      const int cu = u * 4 + w;
      const int du = cu * 64 + l;
      const int row = du >> 3, ch = du & 7, sch = ch ^ (row & 7);
      gl_lds16(A + (size_t)(m0 + row) * Cc + kt * 64 + sch * 8,
               &As[buf * 4096 + cu * 512]);
      gl_lds16(W + (size_t)(c0 + row) * Cc + kt * 64 + sch * 8,
               &Bs[buf * 4096 + cu * 512]);
    }
  };
  auto compute = [&](const int buf) {
    const short* Ab = As + buf * 4096;
    const short* Bbp = Bs + buf * 4096;
#pragma unroll
    for (int kp = 0; kp < 2; ++kp) {
      bf16x8 af[2], bfv[2];
#pragma unroll
      for (int i = 0; i < 2; ++i)
        af[i] = ld_frag(Ab, wr * 32 + i * 16 + lr, kp * 4 + lh);
#pragma unroll
      for (int j = 0; j < 2; ++j)
        bfv[j] = ld_frag(Bbp, wc * 32 + j * 16 + lr, kp * 4 + lh);
      __builtin_amdgcn_s_setprio(1);
#pragma unroll
      for (int i = 0; i < 2; ++i)
#pragma unroll
        for (int j = 0; j < 2; ++j)
          acc[i][j] = __builtin_amdgcn_mfma_f32_16x16x32_bf16(
              af[i], bfv[j], acc[i][j], 0, 0, 0);
      __builtin_amdgcn_s_setprio(0);
    }
  };

  stage(0, 0);
#pragma unroll 1
  for (int kk = 0; kk < 10; kk += 2) {
    stage(1, kk + 1);
    VMCNT(4); SBAR();
    compute(0);
    SBAR();
    stage(0, kk + 2);
    VMCNT(4); SBAR();
    compute(1);
    SBAR();
  }
  stage(1, 11);
  VMCNT(4); SBAR();
  compute(0);
  SBAR();
  VMCNT(0); SBAR();
  compute(1);

#pragma unroll
  for (int j = 0; j < 2; ++j) {
    const int c = c0 + wc * 32 + j * 16 + lr;
    const float bi = bias[c];
#pragma unroll
    for (int i = 0; i < 2; ++i)
#pragma unroll
      for (int r = 0; r < 4; ++r) {
        const int m = m0 + wr * 32 + i * 16 + lh * 4 + r;
        out[(size_t)m * Cc + c] = acc[i][j][r] + bi;
      }
  }
}

// ---------------------------------------------------------------------------
extern "C" void kernel_launch(void* const* d_in, const int* in_sizes, int n_in,
                              void* d_out, int out_size, void* d_ws,
                              size_t ws_size, hipStream_t stream) {
  const float* x = (const float*)d_in[0];
  const float* qkv_w = (const float*)d_in[1];
  const float* proj_w = (const float*)d_in[2];
  const float* proj_b = (const float*)d_in[3];

  float* out = (float*)d_out;
  float* score = out + (size_t)Bb * Nn * Cc;

  const size_t nx = (size_t)Bb * Nn * Cc;   // 3,145,728
  const size_t nwq = (size_t)3 * Cc * Cc;   // 1,769,472
  const size_t npw = (size_t)Cc * Cc;       // 589,824
  short* xb = (short*)d_ws;
  short* wqb = xb + nx;
  short* pwb = wqb + nwq;
  short* Qb = pwb + npw;
  short* Kb = Qb + nx;
  short* Vtb = Kb + nx;
  short* OHb = Vtb + nx;
  float* Linv = (float*)(OHb + nx);

  const int ncvt = (int)((nx + nwq + npw) / 1024);  // 5376 blocks
  cvt3_kernel<<<dim3(ncvt), 256, 0, stream>>>(x, qkv_w, proj_w, xb, (int)nx,
                                              (int)(nx + nwq));
  qkv_mfma<<<dim3(32, 24), 256, 0, stream>>>(xb, wqb, Qb, Kb, Vtb);
  attn_pass1<<<dim3(768), 256, 0, stream>>>(Qb, Kb, Vtb, Linv, OHb);
  score_mfma<<<dim3(2048), 256, 0, stream>>>(Qb, Kb, Linv, score);
  proj_mfma<<<dim3(64, 12), 256, 0, stream>>>(OHb, pwb, proj_b, out);
}